// Round 13
// baseline (261.960 us; speedup 1.0000x reference)
//
#include <hip/hip_runtime.h>
#include <hip/hip_bf16.h>

// GCNEncoder: 2-layer GCN, out-degree norm. N=100000, E=1600000, 128->128->64, fp32 I/O.
// R22 = R21 byte-identical resubmit (R21 hit the same transient broker failure R17 did;
// R18's unchanged resubmit then passed -- no kernel-side cause identified, none plausible).
// R21: R20's fin_gemm merge RACED on deg_inv (gemm role reads it; finalize role writes it;
// same dispatch, no ordering) -> absmax 7e-2. Revert to R19's separate finalize + gemm128
// dispatches. KEEP R20's 32-node agg128_gemm (no cross-block dep; doubles R19's verified
// 16-node kernel: two 16x128 tiles, barrier/node halved, ALL 8 waves in the mini-GEMM).
// Predict: pass restored (absmax ~9.8e-4); agg128_gemm 67 -> ~61-64us (conflicts 0, WRITE
// ~12.5MB); total 261.6 -> ~255-259us.

typedef __attribute__((ext_vector_type(8))) short short8;
typedef __attribute__((ext_vector_type(4))) float floatx4;

__device__ inline unsigned short f2bf(float f) {
    union { float f; unsigned u; } v; v.f = f;
    return (unsigned short)((v.u + 0x8000u) >> 16);  // round-half-away; ties p~2^-17 vs RNE
}
__device__ inline float bf2f(unsigned b) {
    union { unsigned u; float f; } v; v.u = b << 16;
    return v.f;
}
__device__ inline float bf2f_hi(unsigned b) {
    union { unsigned u; float f; } v; v.u = b & 0xFFFF0000u;
    return v.f;
}

#define NBMAX 512   // max 256-node buckets -> N <= 131072 (src < 2^24 for packing)
#define CAP   8192  // fixed bucket capacity; mean 4092 + <=768 alignment pad -> safe
#define CHUNK 8192  // edges per scatter block (R14-proven)
#define SCAP  6144  // LDS staging capacity in finalize (staged path needs cd <= SCAP-768)

// ---- zero bucket cursors (cnt_d | cnt_s contiguous: 2 * NBMAX * 16 ints) ----
__global__ __launch_bounds__(256) void zero_cnt_kernel(int* __restrict__ cnt)
{
    int i = blockIdx.x * 256 + threadIdx.x;
    if (i < NBMAX * 32) cnt[i] = 0;
}

// ---- pass 1: LDS-staged bucket partition; per-bucket run-copy write-out.
//      Blocks [0,EB): pairs by dst-bucket. [EB,2EB): src low-bytes by src-bucket.
//      Blocks >= 2EB: stream-convert x fp32 -> xb bf16, then W1/W2 -> bf16 [n][k]. ----
__global__ __launch_bounds__(1024) void scatter2_kernel(
    const int* __restrict__ src, const int* __restrict__ dst, int E,
    int* __restrict__ cnt_d, int* __restrict__ cnt_s,
    unsigned* __restrict__ pairs, unsigned char* __restrict__ srcs_b, int NB,
    const float* __restrict__ x, unsigned short* __restrict__ xb, int NF8,
    const float* __restrict__ W1, const float* __restrict__ W2,
    unsigned short* __restrict__ Wb1, unsigned short* __restrict__ Wb2)
{
    const int EB = (E + CHUNK - 1) / CHUNK;
    const int t = threadIdx.x;
    const int bid = blockIdx.x;
    if (bid >= 2 * EB) {
        int i = (bid - 2 * EB) * 1024 + t;  // 8-float chunk id
        if (i < NF8) {
            float4 a0 = ((const float4*)x)[(size_t)i * 2];
            float4 a1 = ((const float4*)x)[(size_t)i * 2 + 1];
            uint4 st;
            st.x = (unsigned)f2bf(a0.x) | ((unsigned)f2bf(a0.y) << 16);
            st.y = (unsigned)f2bf(a0.z) | ((unsigned)f2bf(a0.w) << 16);
            st.z = (unsigned)f2bf(a1.x) | ((unsigned)f2bf(a1.y) << 16);
            st.w = (unsigned)f2bf(a1.z) | ((unsigned)f2bf(a1.w) << 16);
            ((uint4*)xb)[i] = st;
        } else {
            int j = i - NF8;                 // W conversion (consumed by later kernels)
            if (j < 128 * 128) {
                int k = j >> 7, n = j & 127;
                Wb1[n * 128 + k] = f2bf(W1[k * 128 + n]);
            } else {
                j -= 128 * 128;
                if (j < 128 * 64) {
                    int k = j >> 6, n = j & 63;
                    Wb2[n * 128 + k] = f2bf(W2[k * 64 + n]);
                }
            }
        }
        return;
    }
    __shared__ int hd[NBMAX], lb[NBMAX], bd[NBMAX], cd_[NBMAX];
    __shared__ unsigned staged[CHUNK];  // 32KB; low 8KB reused as bytes in phase B
    const bool phaseA = (bid < EB);
    const int c = phaseA ? bid : bid - EB;
    const int e0 = c * CHUNK;
    const int e1 = min(e0 + CHUNK, E);
    const int* __restrict__ key = phaseA ? dst : src;

    for (int i = t; i < NB; i += 1024) { hd[i] = 0; cd_[i] = 0; }
    __syncthreads();
    for (int i = e0 + t; i < e1; i += 1024)
        atomicAdd(&hd[key[i] >> 8], 1);
    __syncthreads();
    if (t < NBMAX) lb[t] = (t < NB) ? hd[t] : 0;
    __syncthreads();
    for (int o = 1; o < NBMAX; o <<= 1) {       // inclusive scan over NBMAX entries
        int add = (t >= o && t < NBMAX) ? lb[t - o] : 0;
        __syncthreads();
        if (t < NBMAX) lb[t] += add;
        __syncthreads();
    }
    int* __restrict__ gcnt = phaseA ? cnt_d : cnt_s;
    for (int i = t; i < NB; i += 1024)
        if (hd[i]) bd[i] = atomicAdd(&gcnt[i * 16], hd[i]);
    __syncthreads();

    const int wid = t >> 6, lane = t & 63;
    if (phaseA) {
        for (int i = e0 + t; i < e1; i += 1024) {
            int sv = src[i], dv = dst[i];
            int b = dv >> 8;
            int slot = atomicAdd(&cd_[b], 1);
            staged[lb[b] - hd[b] + slot] = ((unsigned)(dv & 255) << 24) | (unsigned)sv;
        }
        __syncthreads();
        for (int b = wid; b < NB; b += 16) {    // run-copy: wave per bucket
            int len = hd[b];
            if (!len) continue;
            int start = lb[b] - len;
            size_t gbase = (size_t)b * CAP + bd[b];
            for (int j = lane; j < len; j += 64)
                pairs[gbase + j] = staged[start + j];
        }
    } else {
        unsigned char* stb = (unsigned char*)staged;
        for (int i = e0 + t; i < e1; i += 1024) {
            int sv = src[i];
            int b = sv >> 8;
            int slot = atomicAdd(&cd_[b], 1);
            stb[lb[b] - hd[b] + slot] = (unsigned char)(sv & 255);
        }
        __syncthreads();
        for (int b = wid; b < NB; b += 16) {
            int len = hd[b];
            if (!len) continue;
            int start = lb[b] - len;
            size_t gbase = (size_t)b * CAP + bd[b];
            for (int j = lane; j < len; j += 64)
                srcs_b[gbase + j] = stb[start + j];
        }
    }
}

// ---- pass 2 (fused, 512 thr, R18-proven): LDS-staged per-bucket dst sort (4-aligned
//      segments, pads -> dummy index N = zero row) -> sorted_src + (start,end);
//      src hist -> deg_inv ----
__global__ __launch_bounds__(512) void bucket_finalize_kernel(
    const unsigned* __restrict__ pairs, const unsigned char* __restrict__ srcs_b,
    const int* __restrict__ cnt_d, const int* __restrict__ cnt_s,
    int* __restrict__ sorted_src, int2* __restrict__ se,
    float* __restrict__ deg_inv, int N)
{
    const int b = blockIdx.x;
    const int node0 = b << 8;
    const int t = threadIdx.x;
    const size_t base = (size_t)b * CAP;
    __shared__ int hist[256];
    __shared__ int cur[256];
    __shared__ int pre[256];
    __shared__ unsigned ps[SCAP];  // staged pairs (24KB)
    __shared__ int ss[SCAP];       // locally sorted incl. pads (24KB)

    const int cd = cnt_d[b * 16];
    const bool fits = (cd <= SCAP - 768);  // pads add up to 3*256 slots to ss[]
    if (t < 256) hist[t] = 0;
    __syncthreads();
    if (fits) {
        for (int i = t; i < cd; i += 512) {
            unsigned p = pairs[base + i];
            ps[i] = p;
            atomicAdd(&hist[p >> 24], 1);
        }
    } else {
        for (int i = t; i < cd; i += 512)
            atomicAdd(&hist[pairs[base + i] >> 24], 1);
    }
    __syncthreads();
    int v = 0, v4 = 0;
    if (t < 256) {
        v = hist[t];
        v4 = (v + 3) & ~3;  // 4-edge aligned segments (16B int4 idx loads)
        pre[t] = v4;
    }
    __syncthreads();
    for (int o = 1; o < 256; o <<= 1) {
        int add = (t >= o && t < 256) ? pre[t - o] : 0;
        __syncthreads();
        if (t < 256) pre[t] += add;
        __syncthreads();
    }
    int excl = 0;
    if (t < 256) {
        excl = pre[t] - v4;
        cur[t] = excl;
        if (node0 + t < N)
            se[node0 + t] = make_int2((int)base + excl, (int)base + excl + v);
    }
    __syncthreads();
    const int tot4 = pre[255];  // padded total (multiple of 4), <= cd + 3*256
    if (fits) {
        if (t < 256)
            for (int i = v; i < v4; ++i) ss[excl + i] = N;  // pads -> dummy zero row
        __syncthreads();
        for (int i = t; i < cd; i += 512) {
            unsigned p = ps[i];
            int pos = atomicAdd(&cur[p >> 24], 1);
            ss[pos] = (int)(p & 0xFFFFFFu);
        }
        __syncthreads();
        for (int i = t; i < tot4; i += 512)   // coalesced write-out
            sorted_src[base + i] = ss[i];
    } else {
        if (t < 256)
            for (int i = v; i < v4; ++i) sorted_src[base + excl + i] = N;
        __syncthreads();
        for (int i = t; i < cd; i += 512) {
            unsigned p = pairs[base + i];
            int pos = atomicAdd(&cur[p >> 24], 1);
            sorted_src[base + pos] = (int)(p & 0xFFFFFFu);
        }
    }

    __syncthreads();
    if (t < 256) hist[t] = 0;
    __syncthreads();
    const int cs = cnt_s[b * 16];
    for (int i = t; i < cs; i += 512)
        atomicAdd(&hist[srcs_b[base + i]], 1);
    __syncthreads();
    if (t < 256 && node0 + t < N) {
        int d = hist[t];
        deg_inv[node0 + t] = 1.0f / (float)(d < 1 ? 1 : d);
    }
}

// ---------------- MFMA GEMM (layer 1 only), no LDS ----------------
// 64 rows/block (4 waves x 16 rows). A bf16 [M x 128]. deg_inv scale in epilogue.
// Block 0 zeroes output row M (dummy row for agg pads).
__global__ __launch_bounds__(256) void gemm_mfma_kernel(
    const unsigned short* __restrict__ Ab, const unsigned short* __restrict__ Wb,
    const float* __restrict__ scale, unsigned short* __restrict__ Cb, int M)
{
    constexpr int NC = 128, NT = NC / 16;
    const int t = threadIdx.x;
    if (blockIdx.x == 0 && t < NC / 2)
        ((unsigned*)Cb)[(size_t)M * (NC / 2) + t] = 0;  // zero dummy row M
    const int wm = t >> 6;
    const int lane = t & 63;
    const int lm = lane & 15;
    const int lk = (lane >> 4) * 8;

    const int r0 = blockIdx.x * 64 + wm * 16;
    int row = r0 + lm;
    if (row >= M) row = M - 1;  // clamp loads; stores are guarded

    floatx4 acc[NT];
#pragma unroll
    for (int j = 0; j < NT; ++j) acc[j] = (floatx4){0.f, 0.f, 0.f, 0.f};

#pragma unroll
    for (int kk = 0; kk < 4; ++kk) {
        const int kb = kk * 32 + lk;
        short8 af = *(const short8*)&Ab[(size_t)row * 128 + kb];
#pragma unroll
        for (int j = 0; j < NT; ++j) {
            short8 bfr = *(const short8*)&Wb[(size_t)(j * 16 + lm) * 128 + kb];
            acc[j] = __builtin_amdgcn_mfma_f32_16x16x32_bf16(af, bfr, acc[j], 0, 0, 0);
        }
    }

    const int rbase = r0 + (lane >> 4) * 4;
#pragma unroll
    for (int reg = 0; reg < 4; ++reg) {
        int rg = rbase + reg;
        if (rg < M) {
            float di = scale[rg];
#pragma unroll
            for (int j = 0; j < NT; ++j)
                Cb[(size_t)rg * NC + j * 16 + lm] = f2bf(acc[j][reg] * di);
        }
    }
}

// ---------------- aggregate C=128 FUSED with layer-2 GEMM: 32 nodes / 512 threads ----------------
// 16 half-waves, each gathers TWO nodes (blk*32+hw and blk*32+16+hw) -> two 16x128 bf16
// tiles in LDS (XOR-swizzled, no pad rows). Then ALL 8 waves GEMM: wave w -> tile w>>2,
// output cols [(w&3)*16, +16), K=128 (4 MFMA). Stores guarded; OOR rows hold zeros.
#define LD128(vv, ii) uint2 vv = *(const uint2*)&val[(size_t)(ii) * 64 + 2 * l]
#define ACC8_128(I0, I1) do { \
    LD128(v0, I0.x); LD128(v1, I0.y); LD128(v2, I0.z); LD128(v3, I0.w); \
    LD128(v4, I1.x); LD128(v5, I1.y); LD128(v6, I1.z); LD128(v7, I1.w); \
    a0 += ((bf2f(v0.x & 0xFFFF) + bf2f(v1.x & 0xFFFF)) + (bf2f(v2.x & 0xFFFF) + bf2f(v3.x & 0xFFFF))) \
        + ((bf2f(v4.x & 0xFFFF) + bf2f(v5.x & 0xFFFF)) + (bf2f(v6.x & 0xFFFF) + bf2f(v7.x & 0xFFFF))); \
    a1 += ((bf2f_hi(v0.x) + bf2f_hi(v1.x)) + (bf2f_hi(v2.x) + bf2f_hi(v3.x))) \
        + ((bf2f_hi(v4.x) + bf2f_hi(v5.x)) + (bf2f_hi(v6.x) + bf2f_hi(v7.x))); \
    a2 += ((bf2f(v0.y & 0xFFFF) + bf2f(v1.y & 0xFFFF)) + (bf2f(v2.y & 0xFFFF) + bf2f(v3.y & 0xFFFF))) \
        + ((bf2f(v4.y & 0xFFFF) + bf2f(v5.y & 0xFFFF)) + (bf2f(v6.y & 0xFFFF) + bf2f(v7.y & 0xFFFF))); \
    a3 += ((bf2f_hi(v0.y) + bf2f_hi(v1.y)) + (bf2f_hi(v2.y) + bf2f_hi(v3.y))) \
        + ((bf2f_hi(v4.y) + bf2f_hi(v5.y)) + (bf2f_hi(v6.y) + bf2f_hi(v7.y))); \
} while (0)
#define ACC4_128(I0) do { \
    LD128(v0, I0.x); LD128(v1, I0.y); LD128(v2, I0.z); LD128(v3, I0.w); \
    a0 += (bf2f(v0.x & 0xFFFF) + bf2f(v1.x & 0xFFFF)) + (bf2f(v2.x & 0xFFFF) + bf2f(v3.x & 0xFFFF)); \
    a1 += (bf2f_hi(v0.x) + bf2f_hi(v1.x)) + (bf2f_hi(v2.x) + bf2f_hi(v3.x)); \
    a2 += (bf2f(v0.y & 0xFFFF) + bf2f(v1.y & 0xFFFF)) + (bf2f(v2.y & 0xFFFF) + bf2f(v3.y & 0xFFFF)); \
    a3 += (bf2f_hi(v0.y) + bf2f_hi(v1.y)) + (bf2f_hi(v2.y) + bf2f_hi(v3.y)); \
} while (0)

__global__ __launch_bounds__(512) void agg128_gemm_kernel(
    const int2* __restrict__ se, const int* __restrict__ sorted_src,
    const unsigned* __restrict__ val, const float* __restrict__ bias,
    const float* __restrict__ deg_inv, const unsigned short* __restrict__ Wb2,
    unsigned short* __restrict__ g, int N)
{
    __shared__ unsigned short tile[2][16 * 128];  // 8KB, all rows real
    const int t = threadIdx.x;
    if (blockIdx.x == 0 && t < 32) ((unsigned*)g)[(size_t)N * 32 + t] = 0;  // dummy row N

    const int hw = t >> 5;                     // half-wave 0..15
    const int l = t & 31;
    const float4 bv = *(const float4*)&bias[4 * l];

#pragma unroll
    for (int g2 = 0; g2 < 2; ++g2) {
        const int node = blockIdx.x * 32 + g2 * 16 + hw;
        float a0 = 0.f, a1 = 0.f, a2 = 0.f, a3 = 0.f;
        if (node < N) {
            int2 r = se[node];
            int e = r.x;
            const int end4 = r.x + ((r.y - r.x + 3) & ~3);  // pads -> zero row
            if (e + 8 <= end4) {
                int4 i0 = *(const int4*)&sorted_src[e];
                int4 i1 = *(const int4*)&sorted_src[e + 4];
                for (; e + 16 <= end4; e += 8) {
                    int4 n0 = *(const int4*)&sorted_src[e + 8];
                    int4 n1 = *(const int4*)&sorted_src[e + 12];
                    ACC8_128(i0, i1);
                    i0 = n0; i1 = n1;
                }
                ACC8_128(i0, i1);
                e += 8;
            }
            if (e < end4) {  // exactly 4 remain
                int4 i0 = *(const int4*)&sorted_src[e];
                ACC4_128(i0);
            }
            float di = deg_inv[node];
            a0 = fmaxf(a0 + bv.x, 0.f) * di;
            a1 = fmaxf(a1 + bv.y, 0.f) * di;
            a2 = fmaxf(a2 + bv.z, 0.f) * di;
            a3 = fmaxf(a3 + bv.w, 0.f) * di;
        }
        // stage bf16 row hw of tile g2; 16B blocks XOR-swizzled by row
        unsigned w0 = (unsigned)f2bf(a0) | ((unsigned)f2bf(a1) << 16);
        unsigned w1 = (unsigned)f2bf(a2) | ((unsigned)f2bf(a3) << 16);
        unsigned* p = (unsigned*)&tile[g2][hw * 128 + ((((l >> 1) ^ hw) & 15) << 3) + (l & 1) * 4];
        p[0] = w0;
        p[1] = w1;
    }
    __syncthreads();

    // mini-GEMM: wave w (0..7) -> tile w>>2, output cols [(w&3)*16, +16), rows 0..15
    const int w = t >> 6;
    const int ti = w >> 2;
    const int cg = w & 3;
    const int lane = t & 63;
    const int lm = lane & 15;
    const int lk = (lane >> 4) * 8;
    floatx4 acc = (floatx4){0.f, 0.f, 0.f, 0.f};
#pragma unroll
    for (int kk = 0; kk < 4; ++kk) {
        const int kb = kk * 32 + lk;
        const int blk = ((kb >> 3) ^ lm) & 15;   // un-swizzle A read
        short8 af = *(const short8*)&tile[ti][lm * 128 + (blk << 3)];
        short8 bfr = *(const short8*)&Wb2[(size_t)(cg * 16 + lm) * 128 + kb];
        acc = __builtin_amdgcn_mfma_f32_16x16x32_bf16(af, bfr, acc, 0, 0, 0);
    }
    const int rbase = (lane >> 4) * 4;
#pragma unroll
    for (int reg = 0; reg < 4; ++reg) {
        int r = rbase + reg;
        int nd = blockIdx.x * 32 + ti * 16 + r;
        if (nd < N) g[(size_t)nd * 64 + cg * 16 + lm] = f2bf(acc[reg]);
    }
}

// ---------------- aggregate C=64 (bf16 in, fp32 out, +bias): 8-edge unroll + idx prefetch ----------------
#define LD64(vv, ii) unsigned vv = val[(size_t)(ii) * 32 + l]
#define ACC8_64(I0, I1) do { \
    LD64(v0, I0.x); LD64(v1, I0.y); LD64(v2, I0.z); LD64(v3, I0.w); \
    LD64(v4, I1.x); LD64(v5, I1.y); LD64(v6, I1.z); LD64(v7, I1.w); \
    ax += ((bf2f(v0 & 0xFFFF) + bf2f(v1 & 0xFFFF)) + (bf2f(v2 & 0xFFFF) + bf2f(v3 & 0xFFFF))) \
        + ((bf2f(v4 & 0xFFFF) + bf2f(v5 & 0xFFFF)) + (bf2f(v6 & 0xFFFF) + bf2f(v7 & 0xFFFF))); \
    ay += ((bf2f_hi(v0) + bf2f_hi(v1)) + (bf2f_hi(v2) + bf2f_hi(v3))) \
        + ((bf2f_hi(v4) + bf2f_hi(v5)) + (bf2f_hi(v6) + bf2f_hi(v7))); \
} while (0)
#define ACC4_64(I0) do { \
    LD64(v0, I0.x); LD64(v1, I0.y); LD64(v2, I0.z); LD64(v3, I0.w); \
    ax += (bf2f(v0 & 0xFFFF) + bf2f(v1 & 0xFFFF)) + (bf2f(v2 & 0xFFFF) + bf2f(v3 & 0xFFFF)); \
    ay += (bf2f_hi(v0) + bf2f_hi(v1)) + (bf2f_hi(v2) + bf2f_hi(v3)); \
} while (0)

__global__ __launch_bounds__(256) void aggregate64_kernel(
    const int2* __restrict__ se, const int* __restrict__ sorted_src,
    const unsigned* __restrict__ val, const float* __restrict__ bias,
    float* __restrict__ out, int N)
{
    int node = blockIdx.x * 8 + (threadIdx.x >> 5);
    if (node >= N) return;
    int l = threadIdx.x & 31;
    int2 r = se[node];
    int e = r.x;
    const int end4 = r.x + ((r.y - r.x + 3) & ~3);
    float ax = 0.f, ay = 0.f;

    if (e + 8 <= end4) {
        int4 i0 = *(const int4*)&sorted_src[e];
        int4 i1 = *(const int4*)&sorted_src[e + 4];
        for (; e + 16 <= end4; e += 8) {
            int4 n0 = *(const int4*)&sorted_src[e + 8];
            int4 n1 = *(const int4*)&sorted_src[e + 12];
            ACC8_64(i0, i1);
            i0 = n0; i1 = n1;
        }
        ACC8_64(i0, i1);
        e += 8;
    }
    if (e < end4) {
        int4 i0 = *(const int4*)&sorted_src[e];
        ACC4_64(i0);
    }

    float2 o = make_float2(ax + bias[2 * l], ay + bias[2 * l + 1]);
    *(float2*)&out[(size_t)node * 64 + 2 * l] = o;
}

extern "C" void kernel_launch(void* const* d_in, const int* in_sizes, int n_in,
                              void* d_out, int out_size, void* d_ws, size_t ws_size,
                              hipStream_t stream) {
    const float* x  = (const float*)d_in[0];
    const int*   ei = (const int*)d_in[1];
    const float* W1 = (const float*)d_in[2];
    const float* b1 = (const float*)d_in[3];
    const float* W2 = (const float*)d_in[4];
    const float* b2 = (const float*)d_in[5];
    float* out = (float*)d_out;

    const int N = in_sizes[0] / 128;
    const int E = in_sizes[1] / 2;
    const int* src = ei;
    const int* dst = ei + E;
    const int NB = (N + 255) >> 8;

    char* ws = (char*)d_ws;
    size_t off = 0;
    auto alloc = [&](size_t bytes) {
        void* p = ws + off;
        off = (off + bytes + 255) & ~(size_t)255;
        return p;
    };
    float* deg_inv  = (float*)alloc((size_t)N * 4);
    int2*  se       = (int2*)alloc((size_t)N * 8);
    int*   cnt_d    = (int*)alloc((size_t)NBMAX * 16 * 4 * 2);  // cnt_d | cnt_s adjacent
    int*   cnt_s    = cnt_d + (size_t)NBMAX * 16;
    unsigned short* Wb1 = (unsigned short*)alloc((size_t)128 * 128 * 2);
    unsigned short* Wb2 = (unsigned short*)alloc((size_t)64 * 128 * 2);
    unsigned*      pairs  = (unsigned*)alloc((size_t)NBMAX * CAP * 4);
    unsigned char* srcs_b = (unsigned char*)alloc((size_t)NBMAX * CAP);
    int*   sorted_src = (int*)alloc((size_t)NBMAX * CAP * 4);
    unsigned short* h  = (unsigned short*)alloc((size_t)(N + 1) * 128 * 2);  // +1: zero pad row
    unsigned short* xb = (unsigned short*)alloc((size_t)N * 128 * 2);
    // g ((N+1) x 64 bf16) aliases pairs (dead after bucket_finalize) when it fits
    unsigned short* g = ((size_t)(N + 1) * 128 <= (size_t)NBMAX * CAP * 4)
                            ? (unsigned short*)pairs
                            : (unsigned short*)alloc((size_t)(N + 1) * 64 * 2);

    zero_cnt_kernel<<<(NBMAX * 32 + 255) / 256, 256, 0, stream>>>(cnt_d);

    const int EB = (E + CHUNK - 1) / CHUNK;
    const int NF8 = (N * 128) / 8;                     // 8-float chunks (128 % 8 == 0)
    const int WN  = 128 * 128 + 128 * 64;              // W elements to convert
    const int CB  = (NF8 + WN + 1023) / 1024;          // conversion tail blocks
    scatter2_kernel<<<2 * EB + CB, 1024, 0, stream>>>(src, dst, E, cnt_d, cnt_s,
                                                      pairs, srcs_b, NB, x, xb, NF8,
                                                      W1, W2, Wb1, Wb2);
    bucket_finalize_kernel<<<NB, 512, 0, stream>>>(pairs, srcs_b, cnt_d, cnt_s,
                                                   sorted_src, se, deg_inv, N);

    const int gblocks = (N + 63) / 64;
    const int fblocks = (N + 31) / 32;
    const int ablocks = (N + 7) / 8;
    // layer 1: h = bf16(di * (xb @ W1))  -- runs AFTER finalize (deg_inv dependency)
    gemm_mfma_kernel<<<gblocks, 256, 0, stream>>>(xb, Wb1, deg_inv, h, N);
    // fused: per block, two 16-row tiles = relu(Agg(h)+b1)*di ; g = tiles @ W2
    agg128_gemm_kernel<<<fblocks, 512, 0, stream>>>(se, sorted_src, (const unsigned*)h, b1,
                                                    deg_inv, Wb2, g, N);
    // layer 2: out = Agg(g) + b2
    aggregate64_kernel<<<ablocks, 256, 0, stream>>>(se, sorted_src, (const unsigned*)g, b2, out, N);
}